// Round 9
// baseline (734.583 us; speedup 1.0000x reference)
//
#include <hip/hip_runtime.h>
#include <stdint.h>

#define BATCH 256
#define IN_F  1024
#define OUT_F 1024
#define RT    16      // row tiles (IN_F/64)
#define STN   16      // input bit-streams
#define NCOL  16384   // 16 (sg,s) groups * 1024 outputs

typedef int   v4i  __attribute__((ext_vector_type(4)));
typedef int   v16i __attribute__((ext_vector_type(16)));
typedef float v2f  __attribute__((ext_vector_type(2)));

// ws layout: Ap2 4MB | Bp 16MB | flags 512B | cnt 64*64B
#define AP_SZ ((size_t)STN * BATCH * IN_F)
#define BP_SZ ((size_t)64 * NCOL * 16)

// ---------------------------------------------------------------------------
// Fused prep.  Blocks 0..511: pack_B per (g,sg,o).  Blocks 512..767: pack_A
// per (kg,tq,b).  Blocks 768..831: zero d_out (replaces a memset node).
// ---------------------------------------------------------------------------
__global__ __launch_bounds__(256) void pack_fused(
    const float* __restrict__ x, const float* __restrict__ w,
    uint8_t* __restrict__ Ap2, uint8_t* __restrict__ Bp,
    uint32_t* __restrict__ flags, float* __restrict__ out)
{
    if (blockIdx.x < 512) {
        int item = blockIdx.x * 256 + threadIdx.x;      // 131072 items
        int o  = item & 1023;
        int sg = (item >> 10) & 1;
        int g  = item >> 11;                            // 0..63
        const float* wr = w + (size_t)o * IN_F + g * 16;
        uint32_t wq[16];
        #pragma unroll
        for (int j = 0; j < 16; ++j) {
            float wv = wr[j];
            float wf = rintf(fmaxf(sg ? -wv : wv, 0.0f) * 4096.0f);
            wq[j] = (uint32_t)fminf(wf, 65535.0f);
        }
        uint32_t nzmask = 0;
        #pragma unroll
        for (int s = 0; s < 8; ++s) {
            int sh = 14 - 2 * s;
            uint32_t dw[4], nz = 0;
            #pragma unroll
            for (int q = 0; q < 4; ++q) {
                uint32_t d = 0;
                #pragma unroll
                for (int j = 0; j < 4; ++j)
                    d |= ((wq[q * 4 + j] >> sh) & 3u) << (8 * j);
                dw[q] = d;
                nz |= d;
            }
            int sgs = sg * 8 + s;
            *(uint4*)(Bp + (size_t)(g * NCOL + sgs * 1024 + o) * 16) =
                make_uint4(dw[0], dw[1], dw[2], dw[3]);
            nzmask |= (nz ? 1u : 0u) << s;
        }
        int r = g >> 2, ob = o >> 7;                    // wave-uniform
        #pragma unroll
        for (int s = 0; s < 8; ++s) {
            int any = __any((int)((nzmask >> s) & 1u));
            if (any && (threadIdx.x & 63) == 0)
                atomicOr(&flags[(sg * 8 + s) * 8 + ob], 1u << r);
        }
    } else if (blockIdx.x < 768) {
        int item = (blockIdx.x - 512) * 256 + threadIdx.x;  // 65536 items
        int b  = item & 255;
        int tq = (item >> 8) & 3;
        int kg = item >> 10;                            // 0..63
        int r = kg >> 2, f = (kg >> 1) & 1, hi = kg & 1;
        int y = b >> 5, l = hi * 32 + (b & 31);
        const float* xr = x + (size_t)b * IN_F + kg * 16;
        uint32_t xu[16];
        #pragma unroll
        for (int j = 0; j < 16; ++j) {
            float xf = rintf(xr[j] * 4096.0f);          // round half-even
            xf = fminf(fmaxf(xf, -32768.0f), 32767.0f);
            xu[j] = (uint32_t)((int)xf) & 0xFFFFu;      // two's complement
        }
        uint8_t* wbase = Ap2 + ((size_t)(r * 8 + y) * 16) * 2048 + f * 1024 + l * 16;
        #pragma unroll
        for (int tt = 0; tt < 4; ++tt) {
            int t = tq * 4 + tt;
            uint32_t dw[4];
            #pragma unroll
            for (int q = 0; q < 4; ++q) {
                uint32_t d = 0;
                #pragma unroll
                for (int j = 0; j < 4; ++j)
                    d |= ((xu[q * 4 + j] >> t) & 1u) << (8 * j);
                dw[q] = d;
            }
            *(uint4*)(wbase + t * 2048) = make_uint4(dw[0], dw[1], dw[2], dw[3]);
        }
    } else {
        // zero d_out: 64 blocks x 256 threads x 4 x float4 = 1 MB
        int i0 = (blockIdx.x - 768) * 256 + threadIdx.x;
        float4* o4 = (float4*)out;
        float4 z4 = make_float4(0.0f, 0.0f, 0.0f, 0.0f);
        #pragma unroll
        for (int k = 0; k < 4; ++k) o4[k * 16384 + i0] = z4;
    }
}

// ---------------------------------------------------------------------------
// Main.  blockIdx.x = idx*8+z.  Empty flag-words are treated as {bit0}: the
// r=0 B-tile of an empty (sgs,ob) is all-zero so its contribution is exactly
// 0.0 -> total pairs is ALWAYS 128, every (ob,y) region gets exactly
// 16*8 = 128 block-arrivals.  idx -> pair ranked by DESC r-popcount (LPT);
// z = rank&7 of flagged r handled here.  Partial sums atomicAdd into out;
// the 128th-arriving block for a region quantizes it in place (fused
// finalize).  ADC bits identical to verified R1-R8.
// ---------------------------------------------------------------------------
__global__ __launch_bounds__(256, 4) void cim_mfma(
    const uint8_t* __restrict__ Ap2, const uint8_t* __restrict__ Bp,
    const uint32_t* __restrict__ flags, uint32_t* __restrict__ cnt,
    const float* __restrict__ bias, float* __restrict__ out)
{
    const float MAG = 12582912.0f;                  // 2^23 + 2^22
    __shared__ int s_last;
    int tid = threadIdx.x, wid = tid >> 6, l = tid & 63, h2 = l >> 5;

    // ---- LPT worklist over ALL 128 pairs (empty -> artificial bit0) ----
    uint32_t f0 = flags[l], f1 = flags[64 + l];
    if (f0 == 0) f0 = 1u;
    if (f1 == 0) f1 = 1u;
    int pc0 = __popc(f0), pc1 = __popc(f1);
    int idx = blockIdx.x >> 3, z = blockIdx.x & 7;
    unsigned long long lt = (1ULL << l) - 1;
    int rank0 = 0, rank1 = 0;
    #pragma unroll
    for (int v = 16; v >= 1; --v) {
        unsigned long long m0 = __ballot(pc0 == v);
        unsigned long long m1 = __ballot(pc1 == v);
        int c = __popcll(m0) + __popcll(m1);
        rank0 += (pc0 < v) ? c : ((pc0 == v) ? __popcll(m0 & lt) : 0);
        rank1 += (pc1 < v) ? c : ((pc1 == v) ? (__popcll(m0) + __popcll(m1 & lt)) : 0);
    }
    unsigned long long s0 = __ballot(rank0 == idx);
    unsigned long long s1 = __ballot(rank1 == idx);
    int p = s0 ? __builtin_ctzll(s0) : (64 + __builtin_ctzll(s1));
    int sgs = p >> 3, ob = p & 7;
    uint32_t fb = flags[p];
    if (fb == 0) fb = 1u;                           // artificial pair

    int y = blockIdx.y;
    int s = sgs & 7, sg = sgs >> 3;
    int col = sgs * 1024 + ob * 128 + wid * 32 + (l & 31);
    float clane = ldexpf(192.0f / 255.0f, 14 - 2 * s);   // step * 4^(7-s)
    if (sg) clane = -clane;

    v2f acc2[8];
    #pragma unroll
    for (int i = 0; i < 8; ++i) acc2[i] = (v2f)0.0f;
    v16i zero;
    #pragma unroll
    for (int i = 0; i < 16; ++i) zero[i] = 0;

    int rank = 0, nproc = 0;
    for (int r = 0; r < RT; ++r) {
        if (!((fb >> r) & 1u)) continue;            // uniform skip, exact
        if ((rank++ & 7) != z) continue;            // 8-way r-split
        ++nproc;

        v4i bf0 = *(const v4i*)(Bp + ((size_t)(r * 4 + h2)     * NCOL + col) * 16);
        v4i bf1 = *(const v4i*)(Bp + ((size_t)(r * 4 + 2 + h2) * NCOL + col) * 16);

        const uint8_t* abase = Ap2 + ((size_t)(r * 8 + y) * 16) * 2048 + l * 16;
        #pragma unroll 4
        for (int t = 0; t < STN; ++t) {
            const uint8_t* ap = abase + t * 2048;
            v4i af0 = *(const v4i*)ap;              // coalesced 1KB/wave
            v4i af1 = *(const v4i*)(ap + 1024);
            v16i c = __builtin_amdgcn_mfma_i32_32x32x32_i8(af0, bf0, zero, 0, 0, 0);
            c      = __builtin_amdgcn_mfma_i32_32x32x32_i8(af1, bf1, c,    0, 0, 0);
            float wt = (t == 15) ? -32768.0f : (float)(1 << t);
            float cw = clane * wt;                  // exact pow2 scale
            #pragma unroll
            for (int i = 0; i < 8; ++i) {
                v2f af; af.x = (float)c[2 * i]; af.y = (float)c[2 * i + 1];
                v2f tq;
                tq.x = fmaf(af.x, 1.328125f, MAG);  // exact product; add rounds
                tq.y = fmaf(af.y, 1.328125f, MAG);  //   half-even == rintf
                v2f qf = tq - MAG;                  // Sterbenz-exact
                acc2[i].x = fmaf(qf.x, cw, acc2[i].x);
                acc2[i].y = fmaf(qf.y, cw, acc2[i].y);
            }
        }
    }

    if (nproc > 0) {
        int o = ob * 128 + wid * 32 + (l & 31);
        #pragma unroll
        for (int i = 0; i < 16; ++i) {
            int b = y * 32 + (i & 3) + 8 * (i >> 2) + 4 * h2;   // C/D row map
            float v = (i & 1) ? acc2[i >> 1].y : acc2[i >> 1].x;
            atomicAdd(&out[(size_t)b * OUT_F + o], v);
        }
    }

    // ---- arrival + fused finalize (128 arrivals per (ob,y) region) ----
    __threadfence();                                // release our adds
    __syncthreads();                                // all waves' adds drained
    if (tid == 0) {
        unsigned old = atomicAdd(&cnt[(ob * 8 + y) * 16], 1u);  // padded line
        s_last = (old == 127u) ? 1 : 0;
    }
    __syncthreads();
    if (s_last) {
        __threadfence();                            // acquire all adds
        int o0 = ob * 128;
        #pragma unroll
        for (int e = 0; e < 16; ++e) {
            int i = e * 256 + tid;                  // 0..4095
            int bb = i >> 7, oo = i & 127;
            size_t gi = (size_t)(y * 32 + bb) * OUT_F + o0 + oo;
            float ov = __hip_atomic_load(&out[gi], __ATOMIC_RELAXED,
                                         __HIP_MEMORY_SCOPE_AGENT) * 0x1p-24f;
            float q = rintf(ov * 4096.0f);
            q = fminf(fmaxf(q, -32768.0f), 32767.0f);
            out[gi] = q * 0x1p-12f + bias[o0 + oo];
        }
    }
}

// ---------------------------------------------------------------------------
extern "C" void kernel_launch(void* const* d_in, const int* in_sizes, int n_in,
                              void* d_out, int out_size, void* d_ws, size_t ws_size,
                              hipStream_t stream) {
    const float* x    = (const float*)d_in[0];
    const float* w    = (const float*)d_in[1];
    const float* bias = (const float*)d_in[2];
    float* out = (float*)d_out;

    uint8_t*  Ap2   = (uint8_t*)d_ws;
    uint8_t*  Bp    = Ap2 + AP_SZ;
    uint32_t* flags = (uint32_t*)(Bp + BP_SZ);
    uint32_t* cnt   = flags + 128;                  // 64 counters, 64B apart

    hipMemsetAsync(flags, 0, (128 + 64 * 16) * sizeof(uint32_t), stream);
    hipLaunchKernelGGL(pack_fused, dim3(832), dim3(256), 0, stream,
                       x, w, Ap2, Bp, flags, out);
    hipLaunchKernelGGL(cim_mfma, dim3(1024, 8), dim3(256), 0, stream,
                       Ap2, Bp, flags, cnt, bias, out);
}

// Round 10
// 175.274 us; speedup vs baseline: 4.1911x; 4.1911x over previous
//
#include <hip/hip_runtime.h>
#include <stdint.h>

#define BATCH 256
#define IN_F  1024
#define OUT_F 1024
#define RT    16      // row tiles (IN_F/64)
#define STN   16      // input bit-streams
#define NCOL  16384   // 16 (sg,s) groups * 1024 outputs

typedef int   v4i  __attribute__((ext_vector_type(4)));
typedef int   v16i __attribute__((ext_vector_type(16)));
typedef float v2f  __attribute__((ext_vector_type(2)));

// ws layout: Ap2 4MB | Bp 16MB | flags 512B
#define AP_SZ ((size_t)STN * BATCH * IN_F)
#define BP_SZ ((size_t)64 * NCOL * 16)

// ---------------------------------------------------------------------------
// Fused prep (verified R7/R8 form).  Blocks 0..511: pack_B per (g,sg,o).
// Blocks 512..767: pack_A per (kg,tq,b).
// ---------------------------------------------------------------------------
__global__ __launch_bounds__(256) void pack_fused(
    const float* __restrict__ x, const float* __restrict__ w,
    uint8_t* __restrict__ Ap2, uint8_t* __restrict__ Bp,
    uint32_t* __restrict__ flags)
{
    if (blockIdx.x < 512) {
        int item = blockIdx.x * 256 + threadIdx.x;      // 131072 items
        int o  = item & 1023;
        int sg = (item >> 10) & 1;
        int g  = item >> 11;                            // 0..63
        const float* wr = w + (size_t)o * IN_F + g * 16;
        uint32_t wq[16];
        #pragma unroll
        for (int j = 0; j < 16; ++j) {
            float wv = wr[j];
            float wf = rintf(fmaxf(sg ? -wv : wv, 0.0f) * 4096.0f);
            wq[j] = (uint32_t)fminf(wf, 65535.0f);
        }
        uint32_t nzmask = 0;
        #pragma unroll
        for (int s = 0; s < 8; ++s) {
            int sh = 14 - 2 * s;
            uint32_t dw[4], nz = 0;
            #pragma unroll
            for (int q = 0; q < 4; ++q) {
                uint32_t d = 0;
                #pragma unroll
                for (int j = 0; j < 4; ++j)
                    d |= ((wq[q * 4 + j] >> sh) & 3u) << (8 * j);
                dw[q] = d;
                nz |= d;
            }
            int sgs = sg * 8 + s;
            *(uint4*)(Bp + (size_t)(g * NCOL + sgs * 1024 + o) * 16) =
                make_uint4(dw[0], dw[1], dw[2], dw[3]);
            nzmask |= (nz ? 1u : 0u) << s;
        }
        int r = g >> 2, ob = o >> 7;                    // wave-uniform
        #pragma unroll
        for (int s = 0; s < 8; ++s) {
            int any = __any((int)((nzmask >> s) & 1u));
            if (any && (threadIdx.x & 63) == 0)
                atomicOr(&flags[(sg * 8 + s) * 8 + ob], 1u << r);
        }
    } else {
        int item = (blockIdx.x - 512) * 256 + threadIdx.x;  // 65536 items
        int b  = item & 255;
        int tq = (item >> 8) & 3;
        int kg = item >> 10;                            // 0..63
        int r = kg >> 2, f = (kg >> 1) & 1, hi = kg & 1;
        int y = b >> 5, l = hi * 32 + (b & 31);
        const float* xr = x + (size_t)b * IN_F + kg * 16;
        uint32_t xu[16];
        #pragma unroll
        for (int j = 0; j < 16; ++j) {
            float xf = rintf(xr[j] * 4096.0f);          // round half-even
            xf = fminf(fmaxf(xf, -32768.0f), 32767.0f);
            xu[j] = (uint32_t)((int)xf) & 0xFFFFu;      // two's complement
        }
        uint8_t* wbase = Ap2 + ((size_t)(r * 8 + y) * 16) * 2048 + f * 1024 + l * 16;
        #pragma unroll
        for (int tt = 0; tt < 4; ++tt) {
            int t = tq * 4 + tt;
            uint32_t dw[4];
            #pragma unroll
            for (int q = 0; q < 4; ++q) {
                uint32_t d = 0;
                #pragma unroll
                for (int j = 0; j < 4; ++j)
                    d |= ((xu[q * 4 + j] >> t) & 1u) << (8 * j);
                dw[q] = d;
            }
            *(uint4*)(wbase + t * 2048) = make_uint4(dw[0], dw[1], dw[2], dw[3]);
        }
    }
}

// ---------------------------------------------------------------------------
// Main.  Block (oq,y) OWNS output region (32 o-cols, 32 b-rows): 8 waves
// round-robin the (r, sgs) job list derived from flags (ballot scan,
// wave-uniform; r-major order for A-window locality).  Wave accumulates its
// regional partial in regs (R8's bit-exact loop body + ADC), then one LDS
// tree-reduce (fixed order), in-block ACM quantize + bias, direct final
// store.  No atomics, no fences, no finalize kernel.
// ---------------------------------------------------------------------------
__global__ __launch_bounds__(512) void cim_block(
    const uint8_t* __restrict__ Ap2, const uint8_t* __restrict__ Bp,
    const uint32_t* __restrict__ flags, const float* __restrict__ bias,
    float* __restrict__ out)
{
    __shared__ float red[8 * 1024];                 // 32 KB: 8 wave slots
    const float MAG = 12582912.0f;                  // 2^23 + 2^22
    int tid = threadIdx.x, wid = tid >> 6, l = tid & 63, h2 = l >> 5;
    int oq = blockIdx.x, y = blockIdx.y;
    int ob = oq >> 2;

    // lane (l&15) holds the flag word of sgs=(l&15) for this ob
    uint32_t fw = flags[(l & 15) * 8 + ob];

    v2f acc2[8];
    #pragma unroll
    for (int i = 0; i < 8; ++i) acc2[i] = (v2f)0.0f;
    v16i zero;
    #pragma unroll
    for (int i = 0; i < 16; ++i) zero[i] = 0;

    int cnt = 0;
    for (int r = 0; r < RT; ++r) {
        uint32_t smask = (uint32_t)(__ballot((int)((fw >> r) & 1u))) & 0xFFFFu;
        while (smask) {                             // wave-uniform scan
            int sgs = __builtin_ctz(smask);
            smask &= smask - 1;
            if ((cnt++ & 7) != wid) continue;       // round-robin to waves

            int s = sgs & 7, sg = sgs >> 3;
            // clane = +-(192/255) * 2^(14-2s): exact pow2 scale of step
            float clane = __int_as_float((141 - 2 * s) << 23) * (192.0f / 255.0f);
            if (sg) clane = -clane;
            int col = sgs * 1024 + oq * 32 + (l & 31);

            v4i bf0 = *(const v4i*)(Bp + ((size_t)(r * 4 + h2)     * NCOL + col) * 16);
            v4i bf1 = *(const v4i*)(Bp + ((size_t)(r * 4 + 2 + h2) * NCOL + col) * 16);

            const uint8_t* abase = Ap2 + ((size_t)(r * 8 + y) * 16) * 2048 + l * 16;
            #pragma unroll 4
            for (int t = 0; t < STN; ++t) {
                const uint8_t* ap = abase + t * 2048;
                v4i af0 = *(const v4i*)ap;
                v4i af1 = *(const v4i*)(ap + 1024);
                v16i c = __builtin_amdgcn_mfma_i32_32x32x32_i8(af0, bf0, zero, 0, 0, 0);
                c      = __builtin_amdgcn_mfma_i32_32x32x32_i8(af1, bf1, c,    0, 0, 0);
                float wt = (t == 15) ? -32768.0f : (float)(1 << t);
                float cw = clane * wt;              // exact pow2 scale
                #pragma unroll
                for (int i = 0; i < 8; ++i) {
                    v2f af; af.x = (float)c[2 * i]; af.y = (float)c[2 * i + 1];
                    v2f tq;
                    tq.x = fmaf(af.x, 1.328125f, MAG);  // exact prod; add rounds
                    tq.y = fmaf(af.y, 1.328125f, MAG);  //  half-even == rintf
                    v2f qf = tq - MAG;                  // Sterbenz-exact
                    acc2[i].x = fmaf(qf.x, cw, acc2[i].x);
                    acc2[i].y = fmaf(qf.y, cw, acc2[i].y);
                }
            }
        }
    }

    // ---- wave partials -> LDS, tree-reduce (fixed order), finalize ----
    float* slot = red + wid * 1024 + l * 16;
    #pragma unroll
    for (int i = 0; i < 8; ++i) {
        slot[2 * i]     = acc2[i].x;
        slot[2 * i + 1] = acc2[i].y;
    }
    __syncthreads();
    #pragma unroll
    for (int k = 0; k < 2; ++k) {
        int e = k * 512 + tid;                      // 0..1023
        float v = 0.0f;
        #pragma unroll
        for (int w = 0; w < 8; ++w) v += red[w * 1024 + e];
        int ll = e >> 4, i = e & 15;
        int b = y * 32 + (i & 3) + 8 * (i >> 2) + 4 * (ll >> 5);  // C/D row map
        int o = oq * 32 + (ll & 31);
        float ov = v * 0x1p-24f;
        float q = rintf(ov * 4096.0f);
        q = fminf(fmaxf(q, -32768.0f), 32767.0f);
        out[(size_t)b * OUT_F + o] = q * 0x1p-12f + bias[o];
    }
}

// ---------------------------------------------------------------------------
extern "C" void kernel_launch(void* const* d_in, const int* in_sizes, int n_in,
                              void* d_out, int out_size, void* d_ws, size_t ws_size,
                              hipStream_t stream) {
    const float* x    = (const float*)d_in[0];
    const float* w    = (const float*)d_in[1];
    const float* bias = (const float*)d_in[2];
    float* out = (float*)d_out;

    uint8_t*  Ap2   = (uint8_t*)d_ws;
    uint8_t*  Bp    = Ap2 + AP_SZ;
    uint32_t* flags = (uint32_t*)(Bp + BP_SZ);

    hipMemsetAsync(flags, 0, 128 * sizeof(uint32_t), stream);
    hipLaunchKernelGGL(pack_fused, dim3(768), dim3(256), 0, stream,
                       x, w, Ap2, Bp, flags);
    hipLaunchKernelGGL(cim_block, dim3(32, 8), dim3(512), 0, stream,
                       Ap2, Bp, flags, bias, out);
}